// Round 18
// baseline (364.007 us; speedup 1.0000x reference)
//
#include <hip/hip_runtime.h>

#define NN 50000
#define NE 200000
#define NG 512
#define NBK 16       // nodes per bucket
#define NB 3125      // node buckets
#define FN 64
#define FE 16
#define H 32
#define NL 3
#define EPSV 1e-5f

// ================= mega prep (sections) =================
// sec0 (96):   V2[(l*32+i)*512 + f*32+o] = sum_c We[f,c]*Wnn[l][c][i][o];  M likewise
// sec1 (782):  node embedding h = x@W_node + b_node (+agg zero), x staged in LDS
// sec2 (782):  bucket degrees
// sec3 (196):  graph counts via LDS histogram
__global__ void k_prep(const float* __restrict__ Wnn, const float* __restrict__ We,
                       const float* __restrict__ be, const float* __restrict__ Bnn,
                       float* __restrict__ V2, float* __restrict__ M,
                       const int* __restrict__ src, const int* __restrict__ batch,
                       int* __restrict__ degB, float* __restrict__ cnt,
                       const float* __restrict__ x, const float* __restrict__ Wn,
                       const float* __restrict__ bno, float* __restrict__ h,
                       float* __restrict__ agg) {
    __shared__ __align__(16) float smem[6144];   // 24 KB
    int t = threadIdx.x;
    int b = blockIdx.x;
    if (b < 96) {                        // ---- V/M precompute: one block per (l,i)
        int l = b >> 5, i = b & 31;
        float* sWnn = smem;              // [32][32]
        float* sWe  = smem + 1024;       // [16][32]
        for (int j = t; j < 1024; j += 256)
            sWnn[j] = Wnn[((size_t)(l * 32 + (j >> 5))) * 1024 + i * 32 + (j & 31)];
        for (int j = t; j < 512; j += 256) sWe[j] = We[j];
        __syncthreads();
#pragma unroll
        for (int cc = 0; cc < 2; cc++) {
            int c = 2 * t + cc;
            int f = c >> 5, o = c & 31;
            float v = 0.f;
#pragma unroll
            for (int k = 0; k < 32; k++) v += sWe[f * 32 + k] * sWnn[k * 32 + o];
            V2[(size_t)(l * 32 + i) * 512 + c] = v;
        }
        if (t < 32) {
            float m = Bnn[(size_t)l * 1024 + i * 32 + t];
            for (int k = 0; k < 32; k++) m += be[k] * sWnn[k * 32 + t];
            M[l * 1024 + i * 32 + t] = m;
        }
    } else if (b < 878) {                // ---- node embedding: 64 nodes/block, LDS-staged x
        float* sW = smem;                // 2048 (Wn)
        float* sx = smem + 2048;         // 4096 (x tile 64x64)
        for (int j = t; j < FN * H; j += 256) sW[j] = Wn[j];
        int n0 = (b - 96) * 64;
        for (int j = t; j < 1024; j += 256) {
            int row = j >> 4, c4 = j & 15;
            if (n0 + row < NN)
                *(float4*)&sx[row * FN + c4 * 4] =
                    *(const float4*)(x + (size_t)(n0 + row) * FN + c4 * 4);
        }
        __syncthreads();
        int node8 = t >> 5, o = t & 31;
        for (int r = 0; r < 8; r++) {
            int node = r * 8 + node8;
            int n = n0 + node;
            if (n < NN) {
                const float* xr = &sx[node * FN];
                float acc = bno[o];
#pragma unroll 16
                for (int i = 0; i < FN; i++) acc += xr[i] * sW[i * H + o];
                size_t idx = (size_t)n * H + o;
                h[idx] = acc;
                agg[idx] = 0.f;
            }
        }
    } else if (b < 1660) {               // ---- bucket degrees
        int e = (b - 878) * 256 + t;
        if (e < NE) atomicAdd(&degB[src[e] >> 4], 1);
    } else {                             // ---- graph counts: LDS histogram
        float* bins = smem;              // 512
        for (int j = t; j < NG; j += 256) bins[j] = 0.f;
        __syncthreads();
        int n = (b - 1660) * 256 + t;
        if (n < NN) atomicAdd(&bins[batch[n]], 1.f);
        __syncthreads();
        for (int j = t; j < NG; j += 256) {
            float v = bins[j];
            if (v != 0.f) atomicAdd(&cnt[j], v);
        }
    }
}

// ================= bucket scan (single block): rowptrB/cursorB =================
__global__ void k_scanB(const int* __restrict__ degB, int* __restrict__ rowptrB,
                        int* __restrict__ cursorB) {
    __shared__ int ssum[1024];
    int t = threadIdx.x;
    int loc[4];
    int base = t * 4;
    int s = 0;
#pragma unroll
    for (int i = 0; i < 4; i++) {
        int idx = base + i;
        loc[i] = (idx < NB) ? degB[idx] : 0;
        s += loc[i];
    }
    ssum[t] = s;
    for (int off = 1; off < 1024; off <<= 1) {
        __syncthreads();
        int tv = (t >= off) ? ssum[t - off] : 0;
        __syncthreads();
        ssum[t] += tv;
    }
    __syncthreads();
    int run = ssum[t] - s;
#pragma unroll
    for (int i = 0; i < 4; i++) {
        int idx = base + i;
        if (idx < NB) { rowptrB[idx] = run; cursorB[idx] = run; run += loc[i]; }
    }
    if (t == 1023) rowptrB[NB] = ssum[1023];
}

// ================= fill: bucket-sorted packed edge stream (no feature copy) =================
// sdR[p] = dst<<4 | (src&15); eidR[p] = e.
__global__ void k_fill(const int* __restrict__ src, const int* __restrict__ dst,
                       int* __restrict__ cursorB,
                       unsigned* __restrict__ sdR, int* __restrict__ eidR) {
    int e = blockIdx.x * 256 + threadIdx.x;
    if (e >= NE) return;
    int s = src[e];
    int p = atomicAdd(&cursorB[s >> 4], 1);
    sdR[p] = ((unsigned)dst[e] << 4) | (unsigned)(s & 15);
    eidR[p] = e;
}

// ================= fused NNConv v11 (rank-16, 16-node buckets, direct eattr reads) =================
// 256 threads, 16 nodes/block, ~37 KB LDS -> 4 blocks/CU, VGPR cap 128.
// Pre: h (from h0 or BN(z_prev)), z = h@Wr+bc -> global, su = h@M -> LDS.
// Phase A: per half, preload 16 V-rows into regs, 128 FMA per row against shh.
// Phase B: streaming edges, 4/wave/iter; eattr rows read directly (r11->r12 A/B:
// gather hop is free); conflict-free b32 sU reads; 1 atomic/lane.
__global__ __launch_bounds__(256, 4) void k_conv(
    const float* __restrict__ h0, const unsigned* __restrict__ sdR,
    const int* __restrict__ eidR, const float* __restrict__ eattr,
    const float* __restrict__ V2l, const float* __restrict__ Ml,
    const int* __restrict__ rowptrB,
    float* __restrict__ agg, float* __restrict__ z,
    const float* __restrict__ statsPrev, float* __restrict__ statsZero,
    const float* __restrict__ gm, const float* __restrict__ bt,
    const float* __restrict__ Wr, const float* __restrict__ bc, int first) {
    __shared__ __align__(16) float sU[NBK][512];   // 32 KB U tile
    __shared__ __align__(16) float shh[NBK][32];
    __shared__ __align__(16) float su[NBK][32];
    int t = threadIdx.x;
    int nb0 = blockIdx.x * NBK;
    if (blockIdx.x == 0 && t < 64) statsZero[t] = 0.f;

    // ---- pre: h / z / u for the block's 16 nodes (2 passes of 8)
#pragma unroll
    for (int r = 0; r < 2; r++) {
        int node = (t >> 5) + r * 8;
        int o = t & 31;
        size_t idx = (size_t)(nb0 + node) * H + o;
        float hv;
        if (first) {
            hv = h0[idx];
        } else {
            const float invn = 1.0f / (float)NN;
            float mu = statsPrev[o] * invn;
            float var = statsPrev[32 + o] * invn - mu * mu;
            float v = (z[idx] - mu) * rsqrtf(var + EPSV) * gm[o] + bt[o];
            hv = v > 0.f ? v : 0.f;
        }
        shh[node][o] = hv;
        __builtin_amdgcn_wave_barrier();   // shh row (same half-wave) before reads
        float a = bc[o], bacc = 0.f;
#pragma unroll
        for (int i = 0; i < H; i++) {
            float hh = shh[node][i];
            a += hh * Wr[i * H + o];
            bacc += hh * Ml[i * H + o];
        }
        z[idx] = a;
        su[node][o] = bacc;
    }
    __syncthreads();

    // ---- Phase A: U[16][512] in LDS; 16-row register preload per half
    {
        const float* vp = V2l + 2 * t;       // this thread's 2 cols
        float2 acc[NBK];
#pragma unroll
        for (int n = 0; n < NBK; n++) acc[n] = make_float2(0.f, 0.f);
#pragma unroll
        for (int half = 0; half < 2; half++) {
            float2 v[16];
#pragma unroll
            for (int i = 0; i < 16; i++)
                v[i] = *(const float2*)(vp + (size_t)(half * 16 + i) * 512);
#pragma unroll
            for (int i4 = 0; i4 < 4; i4++) {
#pragma unroll
                for (int n = 0; n < NBK; n++) {
                    float4 hv = *(const float4*)&shh[n][half * 16 + i4 * 4];
                    acc[n].x += hv.x * v[i4 * 4 + 0].x + hv.y * v[i4 * 4 + 1].x
                              + hv.z * v[i4 * 4 + 2].x + hv.w * v[i4 * 4 + 3].x;
                    acc[n].y += hv.x * v[i4 * 4 + 0].y + hv.y * v[i4 * 4 + 1].y
                              + hv.z * v[i4 * 4 + 2].y + hv.w * v[i4 * 4 + 3].y;
                }
            }
        }
#pragma unroll
        for (int n = 0; n < NBK; n++)
            *(float2*)&sU[n][2 * t] = acc[n];
    }
    __syncthreads();   // U tile complete

    // ---- Phase B: streaming edge apply (no block barriers, no LDS writes)
    int E0 = rowptrB[blockIdx.x], E1 = rowptrB[blockIdx.x + 1];
    int w = t >> 6;
    int lane = t & 63;
    int hw = lane >> 5;
    int o = lane & 31;
    for (int jb = E0 + 4 * w; jb < E1; jb += 16) {
        int ja = jb + 2 * hw;
        bool a0 = (ja < E1);
        bool a1 = (ja + 1 < E1);
        unsigned sd0 = 0, sd1 = 0;
        float4 e00 = make_float4(0.f, 0.f, 0.f, 0.f), e01 = e00, e02 = e00, e03 = e00;
        float4 e10 = e00, e11 = e00, e12 = e00, e13 = e00;
        if (a0) {
            sd0 = sdR[ja];
            int e = eidR[ja];
            const float4* p0 = (const float4*)(eattr + (size_t)e * FE);
            e00 = p0[0]; e01 = p0[1]; e02 = p0[2]; e03 = p0[3];
        }
        if (a1) {
            sd1 = sdR[ja + 1];
            int e = eidR[ja + 1];
            const float4* p1 = (const float4*)(eattr + (size_t)e * FE);
            e10 = p1[0]; e11 = p1[1]; e12 = p1[2]; e13 = p1[3];
        }
        if (a0) {
            int sn = sd0 & 15;
            unsigned d = sd0 >> 4;
            const float* tp = &sU[sn][0];
            float m = su[sn][o];
            m += e00.x * tp[0 * 32 + o] + e00.y * tp[1 * 32 + o]
               + e00.z * tp[2 * 32 + o] + e00.w * tp[3 * 32 + o];
            m += e01.x * tp[4 * 32 + o] + e01.y * tp[5 * 32 + o]
               + e01.z * tp[6 * 32 + o] + e01.w * tp[7 * 32 + o];
            m += e02.x * tp[8 * 32 + o] + e02.y * tp[9 * 32 + o]
               + e02.z * tp[10 * 32 + o] + e02.w * tp[11 * 32 + o];
            m += e03.x * tp[12 * 32 + o] + e03.y * tp[13 * 32 + o]
               + e03.z * tp[14 * 32 + o] + e03.w * tp[15 * 32 + o];
            atomicAdd(&agg[(size_t)d * H + o], m);
        }
        if (a1) {
            int sn = sd1 & 15;
            unsigned d = sd1 >> 4;
            const float* tp = &sU[sn][0];
            float m = su[sn][o];
            m += e10.x * tp[0 * 32 + o] + e10.y * tp[1 * 32 + o]
               + e10.z * tp[2 * 32 + o] + e10.w * tp[3 * 32 + o];
            m += e11.x * tp[4 * 32 + o] + e11.y * tp[5 * 32 + o]
               + e11.z * tp[6 * 32 + o] + e11.w * tp[7 * 32 + o];
            m += e12.x * tp[8 * 32 + o] + e12.y * tp[9 * 32 + o]
               + e12.z * tp[10 * 32 + o] + e12.w * tp[11 * 32 + o];
            m += e13.x * tp[12 * 32 + o] + e13.y * tp[13 * 32 + o]
               + e13.z * tp[14 * 32 + o] + e13.w * tp[15 * 32 + o];
            atomicAdd(&agg[(size_t)d * H + o], m);
        }
    }
}

// ================= z (+= agg) ; per-channel sum & sumsq =================
// writeback=1: z += agg, agg re-zeroed (inner layers).
// writeback=0: read-only stats pass (last layer; bn_pool reads z+agg itself,
// agg re-zeroed by next launch's k_prep).
__global__ void k_add_stats(float* __restrict__ z, float* __restrict__ agg,
                            float* __restrict__ stats, int writeback) {
    __shared__ float red[256];
    int t = threadIdx.x;
    float s = 0.f, s2 = 0.f;
    for (size_t idx = (size_t)blockIdx.x * 256 + t; idx < (size_t)NN * H;
         idx += (size_t)gridDim.x * 256) {
        float v = z[idx] + agg[idx];
        if (writeback) {
            z[idx] = v;
            agg[idx] = 0.f;
        }
        s += v;
        s2 += v * v;
    }
    red[t] = s;
    __syncthreads();
    for (int st = 128; st >= 32; st >>= 1) {
        if (t < st) red[t] += red[t + st];
        __syncthreads();
    }
    if (t < 32) atomicAdd(&stats[t], red[t]);
    __syncthreads();
    red[t] = s2;
    __syncthreads();
    for (int st = 128; st >= 32; st >>= 1) {
        if (t < st) red[t] += red[t + st];
        __syncthreads();
    }
    if (t < 32) atomicAdd(&stats[32 + t], red[t]);
}

// ================= fused BN+ReLU -> graph pool (last layer; reads z+agg) =================
__global__ void k_bn_pool(const float* __restrict__ z, const float* __restrict__ agg,
                          const float* __restrict__ stats,
                          const float* __restrict__ gm, const float* __restrict__ bt,
                          const int* __restrict__ batch, float* __restrict__ gsum) {
    int idx = blockIdx.x * 256 + threadIdx.x;
    if (idx >= NN * H) return;
    int n = idx >> 5, o = idx & 31;
    const float invn = 1.0f / (float)NN;
    float mu = stats[o] * invn;
    float var = stats[32 + o] * invn - mu * mu;
    float v = (z[idx] + agg[idx] - mu) * rsqrtf(var + EPSV) * gm[o] + bt[o];
    v = v > 0.f ? v : 0.f;
    atomicAdd(&gsum[(size_t)batch[n] * H + o], v);
}

// ================= head =================
__global__ void k_head(const float* __restrict__ gsum, const float* __restrict__ cnt,
                       const float* __restrict__ W2, const float* __restrict__ b2,
                       const float* __restrict__ W3, const float* __restrict__ b3,
                       float* __restrict__ out) {
    __shared__ float sW2[H * 16];
    __shared__ float sW3[16];
    __shared__ float sb2[16];
    int t = threadIdx.x;
    for (int j = t; j < H * 16; j += 256) sW2[j] = W2[j];
    if (t < 16) { sW3[t] = W3[t]; sb2[t] = b2[t]; }
    __syncthreads();
    int g = blockIdx.x * 256 + t;
    if (g >= NG) return;
    float inv = 1.0f / fmaxf(cnt[g], 1.0f);
    float gx[H];
#pragma unroll
    for (int i = 0; i < H; i++) gx[i] = gsum[g * H + i] * inv;
    float o3 = b3[0];
#pragma unroll
    for (int j = 0; j < 16; j++) {
        float hh = sb2[j];
#pragma unroll
        for (int i = 0; i < H; i++) hh += gx[i] * sW2[i * 16 + j];
        hh = hh > 0.f ? hh : 0.f;
        o3 += hh * sW3[j];
    }
    out[g] = o3;
}

extern "C" void kernel_launch(void* const* d_in, const int* in_sizes, int n_in,
                              void* d_out, int out_size, void* d_ws, size_t ws_size,
                              hipStream_t stream) {
    const float* x      = (const float*)d_in[0];
    const float* eattr  = (const float*)d_in[1];
    const float* W_node = (const float*)d_in[2];
    const float* b_node = (const float*)d_in[3];
    const float* W_edge = (const float*)d_in[4];
    const float* b_edge = (const float*)d_in[5];
    const float* W_nn   = (const float*)d_in[6];
    const float* b_nn   = (const float*)d_in[7];
    const float* W_root = (const float*)d_in[8];
    const float* b_conv = (const float*)d_in[9];
    const float* gamma  = (const float*)d_in[10];
    const float* beta   = (const float*)d_in[11];
    const float* W2     = (const float*)d_in[12];
    const float* b2     = (const float*)d_in[13];
    const float* W3     = (const float*)d_in[14];
    const float* b3     = (const float*)d_in[15];
    const int* eidx     = (const int*)d_in[16];
    const int* batch    = (const int*)d_in[17];
    const int* src = eidx;
    const int* dst = eidx + NE;
    float* out = (float*)d_out;

    const size_t NNH = (size_t)NN * H;
    float* ws = (float*)d_ws;
    float* h      = ws;                        // NN*32 (h0 only)
    float* z      = h + NNH;                   // NN*32
    float* agg    = z + NNH;                   // NN*32
    float* stats  = agg + NNH;                 // 2*64 ping-pong
    float* V2     = stats + 128;               // 3*32*512
    float* M      = V2 + (size_t)NL * 32 * 512;// 3*1024
    int*   degB   = (int*)(M + NL * 1024);     // NB
    float* gsum   = (float*)(degB + NB);       // NG*32 (contig with degB,cnt: one memset)
    float* cnt    = gsum + (size_t)NG * H;     // NG
    int*   rowptrB = (int*)(cnt + NG);         // NB+1
    int*   cursorB = rowptrB + NB + 1;         // NB
    unsigned* sdR = (unsigned*)(cursorB + NB); // NE
    int*   eidR   = (int*)(sdR + NE);          // NE

    // zero degB | gsum | cnt in one shot
    hipMemsetAsync(degB, 0, (NB + NG * H + NG) * sizeof(int), stream);

    // mega prep: V/M (96) | node emb (782) | degB (782) | cnt hist (196)
    k_prep<<<96 + 782 + 782 + 196, 256, 0, stream>>>(
        W_nn, W_edge, b_edge, b_nn, V2, M, src, batch, degB, cnt,
        x, W_node, b_node, h, agg);
    k_scanB<<<1, 1024, 0, stream>>>(degB, rowptrB, cursorB);
    k_fill<<<(NE + 255) / 256, 256, 0, stream>>>(src, dst, cursorB, sdR, eidR);

    for (int l = 0; l < NL; l++) {
        float* statsCur  = stats + (l & 1) * 64;
        float* statsPrev = stats + ((l + 1) & 1) * 64;
        int lp = (l > 0) ? (l - 1) : 0;
        k_conv<<<NB, 256, 0, stream>>>(h, sdR, eidR, eattr,
                                       V2 + (size_t)l * 32 * 512,
                                       M + (size_t)l * 1024,
                                       rowptrB, agg, z,
                                       statsPrev, statsCur,
                                       gamma + lp * H, beta + lp * H,
                                       W_root + (size_t)l * H * H, b_conv + l * H,
                                       l == 0 ? 1 : 0);
        k_add_stats<<<512, 256, 0, stream>>>(z, agg, statsCur, (l < NL - 1) ? 1 : 0);
    }

    k_bn_pool<<<(NN * H + 255) / 256, 256, 0, stream>>>(
        z, agg, stats + ((NL - 1) & 1) * 64,
        gamma + (NL - 1) * H, beta + (NL - 1) * H, batch, gsum);
    k_head<<<2, 256, 0, stream>>>(gsum, cnt, W2, b2, W3, b3, out);
}

// Round 19
// 338.626 us; speedup vs baseline: 1.0750x; 1.0750x over previous
//
#include <hip/hip_runtime.h>

#define NN 50000
#define NE 200000
#define NG 512
#define NBK 16       // nodes per bucket
#define NB 3125      // node buckets
#define FN 64
#define FE 16
#define H 32
#define NL 3
#define EPSV 1e-5f

// ================= mega prep (sections) =================
// sec0 (96):   V2[(l*32+i)*512 + f*32+o] = sum_c We[f,c]*Wnn[l][c][i][o];  M likewise
// sec1 (782):  node embedding h = x@W_node + b_node (+agg zero), x staged in LDS
// sec2 (782):  bucket degrees
// sec3 (196):  graph counts via LDS histogram
__global__ void k_prep(const float* __restrict__ Wnn, const float* __restrict__ We,
                       const float* __restrict__ be, const float* __restrict__ Bnn,
                       float* __restrict__ V2, float* __restrict__ M,
                       const int* __restrict__ src, const int* __restrict__ batch,
                       int* __restrict__ degB, float* __restrict__ cnt,
                       const float* __restrict__ x, const float* __restrict__ Wn,
                       const float* __restrict__ bno, float* __restrict__ h,
                       float* __restrict__ agg) {
    __shared__ __align__(16) float smem[6144];   // 24 KB
    int t = threadIdx.x;
    int b = blockIdx.x;
    if (b < 96) {                        // ---- V/M precompute: one block per (l,i)
        int l = b >> 5, i = b & 31;
        float* sWnn = smem;              // [32][32]
        float* sWe  = smem + 1024;       // [16][32]
        for (int j = t; j < 1024; j += 256)
            sWnn[j] = Wnn[((size_t)(l * 32 + (j >> 5))) * 1024 + i * 32 + (j & 31)];
        for (int j = t; j < 512; j += 256) sWe[j] = We[j];
        __syncthreads();
#pragma unroll
        for (int cc = 0; cc < 2; cc++) {
            int c = 2 * t + cc;
            int f = c >> 5, o = c & 31;
            float v = 0.f;
#pragma unroll
            for (int k = 0; k < 32; k++) v += sWe[f * 32 + k] * sWnn[k * 32 + o];
            V2[(size_t)(l * 32 + i) * 512 + c] = v;
        }
        if (t < 32) {
            float m = Bnn[(size_t)l * 1024 + i * 32 + t];
            for (int k = 0; k < 32; k++) m += be[k] * sWnn[k * 32 + t];
            M[l * 1024 + i * 32 + t] = m;
        }
    } else if (b < 878) {                // ---- node embedding: 64 nodes/block, LDS-staged x
        float* sW = smem;                // 2048 (Wn)
        float* sx = smem + 2048;         // 4096 (x tile 64x64)
        for (int j = t; j < FN * H; j += 256) sW[j] = Wn[j];
        int n0 = (b - 96) * 64;
        for (int j = t; j < 1024; j += 256) {
            int row = j >> 4, c4 = j & 15;
            if (n0 + row < NN)
                *(float4*)&sx[row * FN + c4 * 4] =
                    *(const float4*)(x + (size_t)(n0 + row) * FN + c4 * 4);
        }
        __syncthreads();
        int node8 = t >> 5, o = t & 31;
        for (int r = 0; r < 8; r++) {
            int node = r * 8 + node8;
            int n = n0 + node;
            if (n < NN) {
                const float* xr = &sx[node * FN];
                float acc = bno[o];
#pragma unroll 16
                for (int i = 0; i < FN; i++) acc += xr[i] * sW[i * H + o];
                size_t idx = (size_t)n * H + o;
                h[idx] = acc;
                agg[idx] = 0.f;
            }
        }
    } else if (b < 1660) {               // ---- bucket degrees
        int e = (b - 878) * 256 + t;
        if (e < NE) atomicAdd(&degB[src[e] >> 4], 1);
    } else {                             // ---- graph counts: LDS histogram
        float* bins = smem;              // 512
        for (int j = t; j < NG; j += 256) bins[j] = 0.f;
        __syncthreads();
        int n = (b - 1660) * 256 + t;
        if (n < NN) atomicAdd(&bins[batch[n]], 1.f);
        __syncthreads();
        for (int j = t; j < NG; j += 256) {
            float v = bins[j];
            if (v != 0.f) atomicAdd(&cnt[j], v);
        }
    }
}

// ================= bucket scan (single block): rowptrB/cursorB =================
__global__ void k_scanB(const int* __restrict__ degB, int* __restrict__ rowptrB,
                        int* __restrict__ cursorB) {
    __shared__ int ssum[1024];
    int t = threadIdx.x;
    int loc[4];
    int base = t * 4;
    int s = 0;
#pragma unroll
    for (int i = 0; i < 4; i++) {
        int idx = base + i;
        loc[i] = (idx < NB) ? degB[idx] : 0;
        s += loc[i];
    }
    ssum[t] = s;
    for (int off = 1; off < 1024; off <<= 1) {
        __syncthreads();
        int tv = (t >= off) ? ssum[t - off] : 0;
        __syncthreads();
        ssum[t] += tv;
    }
    __syncthreads();
    int run = ssum[t] - s;
#pragma unroll
    for (int i = 0; i < 4; i++) {
        int idx = base + i;
        if (idx < NB) { rowptrB[idx] = run; cursorB[idx] = run; run += loc[i]; }
    }
    if (t == 1023) rowptrB[NB] = ssum[1023];
}

// ================= fill: bucket-sorted packed edge stream =================
// sdR[p] = dst<<4 | (src&15); eaR[p][16] = eattr row (bucket-ordered copy --
// r18 A/B: removing this cost conv +8us/layer from lost locality).
__global__ void k_fill(const int* __restrict__ src, const int* __restrict__ dst,
                       const float* __restrict__ eattr, int* __restrict__ cursorB,
                       unsigned* __restrict__ sdR, float* __restrict__ eaR) {
    int e = blockIdx.x * 256 + threadIdx.x;
    if (e >= NE) return;
    int s = src[e];
    int p = atomicAdd(&cursorB[s >> 4], 1);
    sdR[p] = ((unsigned)dst[e] << 4) | (unsigned)(s & 15);
    const float4* q = (const float4*)(eattr + (size_t)e * FE);
    float4* r = (float4*)(eaR + (size_t)p * FE);
    float4 q0 = q[0], q1 = q[1], q2 = q[2], q3 = q[3];
    r[0] = q0; r[1] = q1; r[2] = q2; r[3] = q3;
}

// ================= fused NNConv (rank-16, 16-node buckets, reg-preload A) =================
// 256 threads, 16 nodes/block, ~37 KB LDS -> 4 blocks/CU, VGPR cap 128.
// Pre: h (from h0 or BN(z_prev)), z = h@Wr+bc -> global, su = h@M -> LDS.
// Phase A: per half, preload 16 V-rows into regs (16 loads in flight), 128 FMA/row.
// Phase B: streaming packed edges (sdR+eaR), 4/wave/iter; conflict-free b32 sU
// reads; 1 coalesced atomicAdd/lane.
__global__ __launch_bounds__(256, 4) void k_conv(
    const float* __restrict__ h0, const unsigned* __restrict__ sdR,
    const float* __restrict__ eaR,
    const float* __restrict__ V2l, const float* __restrict__ Ml,
    const int* __restrict__ rowptrB,
    float* __restrict__ agg, float* __restrict__ z,
    const float* __restrict__ statsPrev, float* __restrict__ statsZero,
    const float* __restrict__ gm, const float* __restrict__ bt,
    const float* __restrict__ Wr, const float* __restrict__ bc, int first) {
    __shared__ __align__(16) float sU[NBK][512];   // 32 KB U tile
    __shared__ __align__(16) float shh[NBK][32];
    __shared__ __align__(16) float su[NBK][32];
    int t = threadIdx.x;
    int nb0 = blockIdx.x * NBK;
    if (blockIdx.x == 0 && t < 64) statsZero[t] = 0.f;

    // ---- pre: h / z / u for the block's 16 nodes (2 passes of 8)
#pragma unroll
    for (int r = 0; r < 2; r++) {
        int node = (t >> 5) + r * 8;
        int o = t & 31;
        size_t idx = (size_t)(nb0 + node) * H + o;
        float hv;
        if (first) {
            hv = h0[idx];
        } else {
            const float invn = 1.0f / (float)NN;
            float mu = statsPrev[o] * invn;
            float var = statsPrev[32 + o] * invn - mu * mu;
            float v = (z[idx] - mu) * rsqrtf(var + EPSV) * gm[o] + bt[o];
            hv = v > 0.f ? v : 0.f;
        }
        shh[node][o] = hv;
        __builtin_amdgcn_wave_barrier();   // shh row (same half-wave) before reads
        float a = bc[o], bacc = 0.f;
#pragma unroll
        for (int i = 0; i < H; i++) {
            float hh = shh[node][i];
            a += hh * Wr[i * H + o];
            bacc += hh * Ml[i * H + o];
        }
        z[idx] = a;
        su[node][o] = bacc;
    }
    __syncthreads();

    // ---- Phase A: U[16][512] in LDS; 16-row register preload per half
    {
        const float* vp = V2l + 2 * t;       // this thread's 2 cols
        float2 acc[NBK];
#pragma unroll
        for (int n = 0; n < NBK; n++) acc[n] = make_float2(0.f, 0.f);
#pragma unroll
        for (int half = 0; half < 2; half++) {
            float2 v[16];
#pragma unroll
            for (int i = 0; i < 16; i++)
                v[i] = *(const float2*)(vp + (size_t)(half * 16 + i) * 512);
#pragma unroll
            for (int i4 = 0; i4 < 4; i4++) {
#pragma unroll
                for (int n = 0; n < NBK; n++) {
                    float4 hv = *(const float4*)&shh[n][half * 16 + i4 * 4];
                    acc[n].x += hv.x * v[i4 * 4 + 0].x + hv.y * v[i4 * 4 + 1].x
                              + hv.z * v[i4 * 4 + 2].x + hv.w * v[i4 * 4 + 3].x;
                    acc[n].y += hv.x * v[i4 * 4 + 0].y + hv.y * v[i4 * 4 + 1].y
                              + hv.z * v[i4 * 4 + 2].y + hv.w * v[i4 * 4 + 3].y;
                }
            }
        }
#pragma unroll
        for (int n = 0; n < NBK; n++)
            *(float2*)&sU[n][2 * t] = acc[n];
    }
    __syncthreads();   // U tile complete

    // ---- Phase B: streaming edge apply (no block barriers, no LDS writes)
    int E0 = rowptrB[blockIdx.x], E1 = rowptrB[blockIdx.x + 1];
    int w = t >> 6;
    int lane = t & 63;
    int hw = lane >> 5;
    int o = lane & 31;
    for (int jb = E0 + 4 * w; jb < E1; jb += 16) {
        int ja = jb + 2 * hw;
        bool a0 = (ja < E1);
        bool a1 = (ja + 1 < E1);
        unsigned sd0 = 0, sd1 = 0;
        float4 e00 = make_float4(0.f, 0.f, 0.f, 0.f), e01 = e00, e02 = e00, e03 = e00;
        float4 e10 = e00, e11 = e00, e12 = e00, e13 = e00;
        if (a0) {
            sd0 = sdR[ja];
            const float4* p0 = (const float4*)(eaR + (size_t)ja * FE);
            e00 = p0[0]; e01 = p0[1]; e02 = p0[2]; e03 = p0[3];
        }
        if (a1) {
            sd1 = sdR[ja + 1];
            const float4* p1 = (const float4*)(eaR + (size_t)(ja + 1) * FE);
            e10 = p1[0]; e11 = p1[1]; e12 = p1[2]; e13 = p1[3];
        }
        if (a0) {
            int sn = sd0 & 15;
            unsigned d = sd0 >> 4;
            const float* tp = &sU[sn][0];
            float m = su[sn][o];
            m += e00.x * tp[0 * 32 + o] + e00.y * tp[1 * 32 + o]
               + e00.z * tp[2 * 32 + o] + e00.w * tp[3 * 32 + o];
            m += e01.x * tp[4 * 32 + o] + e01.y * tp[5 * 32 + o]
               + e01.z * tp[6 * 32 + o] + e01.w * tp[7 * 32 + o];
            m += e02.x * tp[8 * 32 + o] + e02.y * tp[9 * 32 + o]
               + e02.z * tp[10 * 32 + o] + e02.w * tp[11 * 32 + o];
            m += e03.x * tp[12 * 32 + o] + e03.y * tp[13 * 32 + o]
               + e03.z * tp[14 * 32 + o] + e03.w * tp[15 * 32 + o];
            atomicAdd(&agg[(size_t)d * H + o], m);
        }
        if (a1) {
            int sn = sd1 & 15;
            unsigned d = sd1 >> 4;
            const float* tp = &sU[sn][0];
            float m = su[sn][o];
            m += e10.x * tp[0 * 32 + o] + e10.y * tp[1 * 32 + o]
               + e10.z * tp[2 * 32 + o] + e10.w * tp[3 * 32 + o];
            m += e11.x * tp[4 * 32 + o] + e11.y * tp[5 * 32 + o]
               + e11.z * tp[6 * 32 + o] + e11.w * tp[7 * 32 + o];
            m += e12.x * tp[8 * 32 + o] + e12.y * tp[9 * 32 + o]
               + e12.z * tp[10 * 32 + o] + e12.w * tp[11 * 32 + o];
            m += e13.x * tp[12 * 32 + o] + e13.y * tp[13 * 32 + o]
               + e13.z * tp[14 * 32 + o] + e13.w * tp[15 * 32 + o];
            atomicAdd(&agg[(size_t)d * H + o], m);
        }
    }
}

// ================= z (+= agg) ; per-channel sum & sumsq =================
// writeback=1: z += agg, agg re-zeroed (inner layers).
// writeback=0: read-only stats pass (last layer; bn_pool reads z+agg itself,
// agg re-zeroed by next launch's k_prep).
__global__ void k_add_stats(float* __restrict__ z, float* __restrict__ agg,
                            float* __restrict__ stats, int writeback) {
    __shared__ float red[256];
    int t = threadIdx.x;
    float s = 0.f, s2 = 0.f;
    for (size_t idx = (size_t)blockIdx.x * 256 + t; idx < (size_t)NN * H;
         idx += (size_t)gridDim.x * 256) {
        float v = z[idx] + agg[idx];
        if (writeback) {
            z[idx] = v;
            agg[idx] = 0.f;
        }
        s += v;
        s2 += v * v;
    }
    red[t] = s;
    __syncthreads();
    for (int st = 128; st >= 32; st >>= 1) {
        if (t < st) red[t] += red[t + st];
        __syncthreads();
    }
    if (t < 32) atomicAdd(&stats[t], red[t]);
    __syncthreads();
    red[t] = s2;
    __syncthreads();
    for (int st = 128; st >= 32; st >>= 1) {
        if (t < st) red[t] += red[t + st];
        __syncthreads();
    }
    if (t < 32) atomicAdd(&stats[32 + t], red[t]);
}

// ================= fused BN+ReLU -> graph pool (last layer; reads z+agg) =================
__global__ void k_bn_pool(const float* __restrict__ z, const float* __restrict__ agg,
                          const float* __restrict__ stats,
                          const float* __restrict__ gm, const float* __restrict__ bt,
                          const int* __restrict__ batch, float* __restrict__ gsum) {
    int idx = blockIdx.x * 256 + threadIdx.x;
    if (idx >= NN * H) return;
    int n = idx >> 5, o = idx & 31;
    const float invn = 1.0f / (float)NN;
    float mu = stats[o] * invn;
    float var = stats[32 + o] * invn - mu * mu;
    float v = (z[idx] + agg[idx] - mu) * rsqrtf(var + EPSV) * gm[o] + bt[o];
    v = v > 0.f ? v : 0.f;
    atomicAdd(&gsum[(size_t)batch[n] * H + o], v);
}

// ================= head =================
__global__ void k_head(const float* __restrict__ gsum, const float* __restrict__ cnt,
                       const float* __restrict__ W2, const float* __restrict__ b2,
                       const float* __restrict__ W3, const float* __restrict__ b3,
                       float* __restrict__ out) {
    __shared__ float sW2[H * 16];
    __shared__ float sW3[16];
    __shared__ float sb2[16];
    int t = threadIdx.x;
    for (int j = t; j < H * 16; j += 256) sW2[j] = W2[j];
    if (t < 16) { sW3[t] = W3[t]; sb2[t] = b2[t]; }
    __syncthreads();
    int g = blockIdx.x * 256 + t;
    if (g >= NG) return;
    float inv = 1.0f / fmaxf(cnt[g], 1.0f);
    float gx[H];
#pragma unroll
    for (int i = 0; i < H; i++) gx[i] = gsum[g * H + i] * inv;
    float o3 = b3[0];
#pragma unroll
    for (int j = 0; j < 16; j++) {
        float hh = sb2[j];
#pragma unroll
        for (int i = 0; i < H; i++) hh += gx[i] * sW2[i * 16 + j];
        hh = hh > 0.f ? hh : 0.f;
        o3 += hh * sW3[j];
    }
    out[g] = o3;
}

extern "C" void kernel_launch(void* const* d_in, const int* in_sizes, int n_in,
                              void* d_out, int out_size, void* d_ws, size_t ws_size,
                              hipStream_t stream) {
    const float* x      = (const float*)d_in[0];
    const float* eattr  = (const float*)d_in[1];
    const float* W_node = (const float*)d_in[2];
    const float* b_node = (const float*)d_in[3];
    const float* W_edge = (const float*)d_in[4];
    const float* b_edge = (const float*)d_in[5];
    const float* W_nn   = (const float*)d_in[6];
    const float* b_nn   = (const float*)d_in[7];
    const float* W_root = (const float*)d_in[8];
    const float* b_conv = (const float*)d_in[9];
    const float* gamma  = (const float*)d_in[10];
    const float* beta   = (const float*)d_in[11];
    const float* W2     = (const float*)d_in[12];
    const float* b2     = (const float*)d_in[13];
    const float* W3     = (const float*)d_in[14];
    const float* b3     = (const float*)d_in[15];
    const int* eidx     = (const int*)d_in[16];
    const int* batch    = (const int*)d_in[17];
    const int* src = eidx;
    const int* dst = eidx + NE;
    float* out = (float*)d_out;

    const size_t NNH = (size_t)NN * H;
    float* ws = (float*)d_ws;
    float* h      = ws;                        // NN*32 (h0 only)
    float* z      = h + NNH;                   // NN*32
    float* agg    = z + NNH;                   // NN*32
    float* stats  = agg + NNH;                 // 2*64 ping-pong
    float* V2     = stats + 128;               // 3*32*512
    float* M      = V2 + (size_t)NL * 32 * 512;// 3*1024
    int*   degB   = (int*)(M + NL * 1024);     // NB
    float* gsum   = (float*)(degB + NB);       // NG*32 (contig with degB,cnt: one memset)
    float* cnt    = gsum + (size_t)NG * H;     // NG
    int*   rowptrB = (int*)(cnt + NG);         // NB+1
    int*   cursorB = rowptrB + NB + 1;         // NB
    unsigned* sdR = (unsigned*)(cursorB + NB); // NE
    float* eaR    = (float*)(sdR + NE);        // NE*16

    // zero degB | gsum | cnt in one shot
    hipMemsetAsync(degB, 0, (NB + NG * H + NG) * sizeof(int), stream);

    // mega prep: V/M (96) | node emb (782) | degB (782) | cnt hist (196)
    k_prep<<<96 + 782 + 782 + 196, 256, 0, stream>>>(
        W_nn, W_edge, b_edge, b_nn, V2, M, src, batch, degB, cnt,
        x, W_node, b_node, h, agg);
    k_scanB<<<1, 1024, 0, stream>>>(degB, rowptrB, cursorB);
    k_fill<<<(NE + 255) / 256, 256, 0, stream>>>(src, dst, eattr, cursorB, sdR, eaR);

    for (int l = 0; l < NL; l++) {
        float* statsCur  = stats + (l & 1) * 64;
        float* statsPrev = stats + ((l + 1) & 1) * 64;
        int lp = (l > 0) ? (l - 1) : 0;
        k_conv<<<NB, 256, 0, stream>>>(h, sdR, eaR,
                                       V2 + (size_t)l * 32 * 512,
                                       M + (size_t)l * 1024,
                                       rowptrB, agg, z,
                                       statsPrev, statsCur,
                                       gamma + lp * H, beta + lp * H,
                                       W_root + (size_t)l * H * H, b_conv + l * H,
                                       l == 0 ? 1 : 0);
        k_add_stats<<<512, 256, 0, stream>>>(z, agg, statsCur, (l < NL - 1) ? 1 : 0);
    }

    k_bn_pool<<<(NN * H + 255) / 256, 256, 0, stream>>>(
        z, agg, stats + ((NL - 1) & 1) * 64,
        gamma + (NL - 1) * H, beta + (NL - 1) * H, batch, gsum);
    k_head<<<2, 256, 0, stream>>>(gsum, cnt, W2, b2, W3, b3, out);
}